// Round 6
// baseline (355.094 us; speedup 1.0000x reference)
//
#include <hip/hip_runtime.h>
#include <math.h>

// AttnBlock: GroupNorm(32) -> q,k,v 1x1 -> spatial attention -> proj -> resid.
// Round 6: attn with 32 queries/wave (2 B-frags per A-frag read -> half the
// per-work LDS frag traffic), 256 q/block, KSPLIT=4, normalized bf16 partial-O
// in [n][c]; proj rewritten as frag-direct bf16 MFMA (A=Wp^T via prep kernel,
// B = 4-way merged partial frags in registers), zero LDS, fused bias+resid.

#define BB 4
#define CCH 256
#define NSP 4096
#define EPSV 1e-5f
#define ATTN_SCALE 0.0625f  // 256^-0.5
#define RSQRT2 0.70710678118654752440f
#define KSPLIT 4
#define TILES_PER_PART 16   // 4096 / 64 / KSPLIT

typedef __attribute__((ext_vector_type(8))) short bf16x8;
typedef __attribute__((ext_vector_type(4))) short bf16x4;
typedef __attribute__((ext_vector_type(4))) float f32x4;

__device__ __forceinline__ short f2bf(float f) {
  union { float f; unsigned u; } a; a.f = f;
  unsigned r = a.u + 0x7fffu + ((a.u >> 16) & 1u);  // RTN-even
  return (short)(r >> 16);
}
__device__ __forceinline__ float bf2f(short s) {
  union { unsigned u; float f; } a;
  a.u = ((unsigned)(unsigned short)s) << 16;
  return a.f;
}

__device__ __forceinline__ f32x4 mfma16x16x16(bf16x4 a, bf16x4 b, f32x4 c) {
#if __has_builtin(__builtin_amdgcn_mfma_f32_16x16x16bf16_1k)
  return __builtin_amdgcn_mfma_f32_16x16x16bf16_1k(a, b, c, 0, 0, 0);
#else
  asm volatile("v_mfma_f32_16x16x16_bf16 %0, %1, %2, %0"
               : "+v"(c) : "v"(a), "v"(b));
  return c;
#endif
}

// ---------------- GroupNorm (unchanged) ----------------
__global__ __launch_bounds__(256) void gn_kernel(
    const float* __restrict__ x, const float* __restrict__ gw,
    const float* __restrict__ gb, float* __restrict__ h) {
  int b = blockIdx.x >> 5;
  int g = blockIdx.x & 31;
  size_t base = ((size_t)b * CCH + (size_t)g * 8) * NSP;
  const float4* xv = (const float4*)(x + base);
  int tid = threadIdx.x;
  float s = 0.f, ss = 0.f;
  for (int i = tid; i < 8192; i += 256) {
    float4 v = xv[i];
    s += (v.x + v.y) + (v.z + v.w);
    ss += (v.x * v.x + v.y * v.y) + (v.z * v.z + v.w * v.w);
  }
#pragma unroll
  for (int off = 32; off > 0; off >>= 1) {
    s += __shfl_down(s, off, 64);
    ss += __shfl_down(ss, off, 64);
  }
  __shared__ float rs[4], rss[4], stat[2];
  int wv = tid >> 6;
  if ((tid & 63) == 0) { rs[wv] = s; rss[wv] = ss; }
  __syncthreads();
  if (tid == 0) {
    float S = rs[0] + rs[1] + rs[2] + rs[3];
    float SS = rss[0] + rss[1] + rss[2] + rss[3];
    float mean = S * (1.f / 32768.f);
    float var = SS * (1.f / 32768.f) - mean * mean;
    stat[0] = mean;
    stat[1] = rsqrtf(var + EPSV);
  }
  __syncthreads();
  float mean = stat[0], rstd = stat[1];
  float4* hv = (float4*)(h + base);
  for (int i = tid; i < 8192; i += 256) {
    int c = g * 8 + (i >> 10);
    float a = gw[c] * rstd;
    float bb = gb[c] - mean * a;
    float4 v = xv[i];
    float4 o;
    o.x = v.x * a + bb; o.y = v.y * a + bb;
    o.z = v.z * a + bb; o.w = v.w * a + bb;
    hv[i] = o;
  }
}

// ---------------- QKV (unchanged from round 5) ----------------
__global__ __launch_bounds__(256) void qkv_kernel(
    const float* __restrict__ h,
    const float* __restrict__ Wq, const float* __restrict__ bq,
    const float* __restrict__ Wk, const float* __restrict__ bk,
    const float* __restrict__ Wv, const float* __restrict__ bv,
    short* __restrict__ qo, short* __restrict__ ko, short* __restrict__ vo) {
  __shared__ __align__(16) float Ws[32][64];
  __shared__ __align__(16) float Hs[32][64];
  __shared__ __align__(16) float Ts[64][68];
  int n0 = blockIdx.x * 64;
  int d0 = blockIdx.y * 64;
  int b = blockIdx.z & 3;
  int op = blockIdx.z >> 2;
  const float* W = (op == 0) ? Wq : (op == 1) ? Wk : Wv;
  const float* bias = (op == 0) ? bq : (op == 1) ? bk : bv;
  const float* hb = h + (size_t)b * CCH * NSP;
  int tid = threadIdx.x;
  int tx = tid & 15, ty = tid >> 4;
  int srow = tid >> 4, sc4 = tid & 15;
  float acc[4][4] = {};
  for (int c0 = 0; c0 < CCH; c0 += 32) {
#pragma unroll
    for (int i = 0; i < 2; ++i) {
      int row = srow + 16 * i;
      *(float4*)&Ws[row][sc4 * 4] =
          *(const float4*)&W[(size_t)(c0 + row) * CCH + d0 + sc4 * 4];
      *(float4*)&Hs[row][sc4 * 4] =
          *(const float4*)&hb[(size_t)(c0 + row) * NSP + n0 + sc4 * 4];
    }
    __syncthreads();
    for (int cc = 0; cc < 32; ++cc) {
      float4 w4 = *(const float4*)&Ws[cc][ty * 4];
      float4 h4 = *(const float4*)&Hs[cc][tx * 4];
      const float wr[4] = {w4.x, w4.y, w4.z, w4.w};
      const float hr[4] = {h4.x, h4.y, h4.z, h4.w};
#pragma unroll
      for (int i = 0; i < 4; ++i)
#pragma unroll
        for (int j = 0; j < 4; ++j) acc[i][j] += wr[i] * hr[j];
    }
    __syncthreads();
  }
  if (op == 2) {  // v: [c][n] bf16
    short* ob = vo + (size_t)b * CCH * NSP;
#pragma unroll
    for (int i = 0; i < 4; ++i) {
      int d = d0 + ty * 4 + i;
      float bi = bias[d];
      bf16x4 r;
      r[0] = f2bf(acc[i][0] + bi); r[1] = f2bf(acc[i][1] + bi);
      r[2] = f2bf(acc[i][2] + bi); r[3] = f2bf(acc[i][3] + bi);
      *(bf16x4*)(ob + (size_t)d * NSP + n0 + tx * 4) = r;
    }
  } else {  // q/k: transpose to [n][c] bf16 (q pre-scaled)
    float sc = (op == 0) ? ATTN_SCALE : 1.f;
#pragma unroll
    for (int i = 0; i < 4; ++i) {
      int d = d0 + ty * 4 + i;
      float bi = bias[d];
#pragma unroll
      for (int j = 0; j < 4; ++j) Ts[tx * 4 + j][ty * 4 + i] = (acc[i][j] + bi) * sc;
    }
    __syncthreads();
    short* ob = ((op == 0) ? qo : ko) + (size_t)b * NSP * CCH;
#pragma unroll
    for (int it = 0; it < 2; ++it) {
      int idx = tid + 256 * it;
      int row = idx >> 3, c8 = (idx & 7) * 8;
      float4 f0 = *(float4*)&Ts[row][c8];
      float4 f1 = *(float4*)&Ts[row][c8 + 4];
      bf16x8 r;
      r[0] = f2bf(f0.x); r[1] = f2bf(f0.y); r[2] = f2bf(f0.z); r[3] = f2bf(f0.w);
      r[4] = f2bf(f1.x); r[5] = f2bf(f1.y); r[6] = f2bf(f1.z); r[7] = f2bf(f1.w);
      *(bf16x8*)(ob + (size_t)(n0 + row) * CCH + d0 + c8) = r;
    }
  }
}

// ---------------- prep: Wp [c][d] fp32 -> Wpt [d][c] bf16 ----------------
__global__ __launch_bounds__(256) void prep_wpt(
    const float* __restrict__ Wp, short* __restrict__ wpt) {
  __shared__ float T[64][65];
  int c0 = blockIdx.x * 64, d0 = blockIdx.y * 64;
  int tid = threadIdx.x;
#pragma unroll
  for (int i = 0; i < 16; ++i) {
    int idx = tid + 256 * i;
    int row = idx >> 6, col = idx & 63;
    T[row][col] = Wp[(size_t)(c0 + row) * CCH + d0 + col];
  }
  __syncthreads();
#pragma unroll
  for (int i = 0; i < 16; ++i) {
    int idx = tid + 256 * i;
    int dr = idx >> 6, cc = idx & 63;
    wpt[(size_t)(d0 + dr) * CCH + c0 + cc] = f2bf(T[cc][dr]);
  }
}

// ---------------- flash attention: 8 waves, 32 q/wave, 256 q/block ---------
// q,k: [b][n][c] bf16 (q pre-scaled); v: [b][c][n] bf16.
// Writes NORMALIZED partial O^T [kh][b][n][c] bf16 + m,l stats [kh][b][n].
__global__ __launch_bounds__(512, 2) void attn_kernel(
    const short* __restrict__ q, const short* __restrict__ k,
    const short* __restrict__ v, short* __restrict__ po,
    float* __restrict__ pm, float* __restrict__ pl) {
  __shared__ __align__(16) unsigned char smem[65536];   // 64 KB
  short* Ks = (short*)smem;            // [64 m][256 c] swizzled (also Q stage)
  short* Vs = (short*)(smem + 32768);  // [256 c][64 m] swizzled
  short* Fo = (short*)smem;            // epilogue [64 n][264 c] bf16

  int bx = blockIdx.x;
  int b = bx & 3;
  int n0 = ((bx >> 2) & 15) << 8;   // 256-query block
  int kh = bx >> 6;                 // key quarter
  const short* qb = q + (size_t)b * NSP * CCH;
  const short* kb = k + (size_t)b * NSP * CCH;
  const short* vb = v + (size_t)b * CCH * NSP;
  int tid = threadIdx.x;
  int w = tid >> 6, lane = tid & 63, quad = lane >> 4, l16 = lane & 15;

  // staging geometry (512 threads)
  int krow = tid >> 3, kch8 = tid & 7;   // K/Q: row krow, chunks kch8+8i
  int ksw = (kch8 ^ (krow & 7)) * 8;     // swizzled base (chunk+8i keeps row&7)
  int vrow = tid >> 1, vc = tid & 1;     // V: row vrow, chunks vc*4+i

  // ---- stage Q in 4 passes of 64 rows through Ks; extract B-frags ----
  bf16x8 a_q[2][8];
#pragma unroll
  for (int p = 0; p < 4; ++p) {
    const short* qp = qb + (size_t)(n0 + p * 64 + krow) * CCH + kch8 * 8;
#pragma unroll
    for (int i = 0; i < 4; ++i)
      *(bf16x8*)(Ks + krow * 256 + ksw + 64 * i) = *(const bf16x8*)(qp + 64 * i);
    __syncthreads();
    if ((w >> 1) == p) {
#pragma unroll
      for (int nb = 0; nb < 2; ++nb) {
        int row = (w & 1) * 32 + nb * 16 + l16;
#pragma unroll
        for (int kc = 0; kc < 8; ++kc)
          a_q[nb][kc] =
              *(bf16x8*)(Ks + row * 256 + (((kc * 4 + quad) ^ (row & 7)) * 8));
      }
    }
    __syncthreads();
  }

  int mbase = kh * TILES_PER_PART * 64;
  // ---- stage tile 0 ----
  {
    const short* kp = kb + (size_t)(mbase + krow) * CCH + kch8 * 8;
#pragma unroll
    for (int i = 0; i < 4; ++i)
      *(bf16x8*)(Ks + krow * 256 + ksw + 64 * i) = *(const bf16x8*)(kp + 64 * i);
    const short* vp = vb + (size_t)vrow * NSP + mbase;
#pragma unroll
    for (int i = 0; i < 4; ++i) {
      int c = vc * 4 + i;
      *(bf16x8*)(Vs + vrow * 64 + ((c ^ (vrow & 7)) * 8)) =
          *(const bf16x8*)(vp + c * 8);
    }
  }
  __syncthreads();

  f32x4 accO[2][16];  // [nb][cb]: ch = cb*16+quad*4+r, query = w*32+nb*16+l16
#pragma unroll
  for (int nb = 0; nb < 2; ++nb)
#pragma unroll
    for (int cb = 0; cb < 16; ++cb) accO[nb][cb] = (f32x4){0.f, 0.f, 0.f, 0.f};
  float m_run[2] = {-1e30f, -1e30f}, l_run[2] = {0.f, 0.f};

#pragma unroll 1
  for (int t = 0; t < TILES_PER_PART; ++t) {
    // ---- S^T = K Q^T : rows = 64 keys, cols = 2x16 queries ----
    f32x4 s[2][4];
#pragma unroll
    for (int nb = 0; nb < 2; ++nb)
#pragma unroll
      for (int mb = 0; mb < 4; ++mb) s[nb][mb] = (f32x4){0.f, 0.f, 0.f, 0.f};
#pragma unroll
    for (int kc = 0; kc < 8; ++kc) {
#pragma unroll
      for (int mb = 0; mb < 4; ++mb) {
        int row = mb * 16 + l16;
        bf16x8 kf = *(bf16x8*)(Ks + row * 256 + (((kc * 4 + quad) ^ (row & 7)) * 8));
        s[0][mb] = __builtin_amdgcn_mfma_f32_16x16x32_bf16(kf, a_q[0][kc], s[0][mb], 0, 0, 0);
        s[1][mb] = __builtin_amdgcn_mfma_f32_16x16x32_bf16(kf, a_q[1][kc], s[1][mb], 0, 0, 0);
      }
    }
    // ---- online softmax per nb (one query per lane) ----
    bf16x4 pb[2][4];
#pragma unroll
    for (int nb = 0; nb < 2; ++nb) {
      float mx = -1e30f;
#pragma unroll
      for (int mb = 0; mb < 4; ++mb)
#pragma unroll
        for (int r = 0; r < 4; ++r) mx = fmaxf(mx, s[nb][mb][r]);
      mx = fmaxf(mx, __shfl_xor(mx, 16));
      mx = fmaxf(mx, __shfl_xor(mx, 32));
      float mnew = fmaxf(m_run[nb], mx);
      float alpha = __expf(m_run[nb] - mnew);
      m_run[nb] = mnew;
      float ls = 0.f;
#pragma unroll
      for (int mb = 0; mb < 4; ++mb)
#pragma unroll
        for (int r = 0; r < 4; ++r) {
          float p = __expf(s[nb][mb][r] - mnew);
          ls += p;
          pb[nb][mb][r] = f2bf(p);
        }
      ls += __shfl_xor(ls, 16);
      ls += __shfl_xor(ls, 32);
      l_run[nb] = l_run[nb] * alpha + ls;
#pragma unroll
      for (int cb = 0; cb < 16; ++cb) accO[nb][cb] *= alpha;
    }
    // ---- O^T += V P^T : A = V-frag (b64), B = pb from registers ----
#pragma unroll
    for (int kw = 0; kw < 4; ++kw) {
#pragma unroll
      for (int cb = 0; cb < 16; ++cb) {
        int row = cb * 16 + l16;
        int chunk = (kw * 2 + (quad >> 1)) ^ (row & 7);
        bf16x4 vf = *(bf16x4*)(Vs + row * 64 + chunk * 8 + (quad & 1) * 4);
        accO[0][cb] = mfma16x16x16(vf, pb[0][kw], accO[0][cb]);
        accO[1][cb] = mfma16x16x16(vf, pb[1][kw], accO[1][cb]);
      }
    }
    __syncthreads();
    if (t < TILES_PER_PART - 1) {
      int m0 = mbase + (t + 1) * 64;
      const short* kp = kb + (size_t)(m0 + krow) * CCH + kch8 * 8;
      bf16x8 kr[4];
#pragma unroll
      for (int i = 0; i < 4; ++i) kr[i] = *(const bf16x8*)(kp + 64 * i);
      const short* vp = vb + (size_t)vrow * NSP + m0;
      bf16x8 vr[4];
#pragma unroll
      for (int i = 0; i < 4; ++i) vr[i] = *(const bf16x8*)(vp + (vc * 4 + i) * 8);
#pragma unroll
      for (int i = 0; i < 4; ++i)
        *(bf16x8*)(Ks + krow * 256 + ksw + 64 * i) = kr[i];
#pragma unroll
      for (int i = 0; i < 4; ++i) {
        int c = vc * 4 + i;
        *(bf16x8*)(Vs + vrow * 64 + ((c ^ (vrow & 7)) * 8)) = vr[i];
      }
      __syncthreads();
    }
  }
  // ---- stats ----
  size_t sbase = ((size_t)kh * BB + b) * NSP + n0;
  if (quad == 0) {
#pragma unroll
    for (int nb = 0; nb < 2; ++nb) {
      pm[sbase + w * 32 + nb * 16 + l16] = m_run[nb];
      pl[sbase + w * 32 + nb * 16 + l16] = l_run[nb];
    }
  }
  // ---- epilogue: normalized bf16 O^T -> po [kh][b][n][c], LDS transpose ----
  float linv[2] = {1.f / l_run[0], 1.f / l_run[1]};
  short* ob = po + ((size_t)kh * BB + b) * NSP * CCH;
#pragma unroll
  for (int p = 0; p < 4; ++p) {
    __syncthreads();
    if ((w >> 1) == p) {
#pragma unroll
      for (int nb = 0; nb < 2; ++nb) {
        int nloc = (w & 1) * 32 + nb * 16 + l16;
#pragma unroll
        for (int cb = 0; cb < 16; ++cb)
#pragma unroll
          for (int r = 0; r < 4; ++r)
            Fo[nloc * 264 + cb * 16 + quad * 4 + r] = f2bf(accO[nb][cb][r] * linv[nb]);
      }
    }
    __syncthreads();
    int row = tid >> 3, seg = tid & 7;
    short* dst = ob + (size_t)(n0 + p * 64 + row) * CCH + seg * 32;
#pragma unroll
    for (int i = 0; i < 4; ++i)
      *(bf16x8*)(dst + i * 8) = *(bf16x8*)(Fo + row * 264 + seg * 32 + i * 8);
  }
}

// ------- proj: frag-direct MFMA, 4-way merge in registers, +bias+resid ------
// po: [kh][b][n][c] bf16 normalized; out[d][n] = Wp^T . (merged h) + bp + x.
__global__ __launch_bounds__(256) void proj_kernel(
    const short* __restrict__ po, const float* __restrict__ pm,
    const float* __restrict__ pl, const short* __restrict__ wpt,
    const float* __restrict__ bp, const float* __restrict__ x,
    float* __restrict__ out) {
  int n0 = blockIdx.x * 64;
  int dh = blockIdx.y * 128;
  int b = blockIdx.z;
  int tid = threadIdx.x;
  int w = tid >> 6, lane = tid & 63, quad = lane >> 4, l16 = lane & 15;
  int n = n0 + w * 16 + l16;

  // merge weights for this lane's query n
  float wgt[KSPLIT];
  {
    float m[KSPLIT], l[KSPLIT];
#pragma unroll
    for (int kh = 0; kh < KSPLIT; ++kh) {
      m[kh] = pm[((size_t)kh * BB + b) * NSP + n];
      l[kh] = pl[((size_t)kh * BB + b) * NSP + n];
    }
    float M = fmaxf(fmaxf(m[0], m[1]), fmaxf(m[2], m[3]));
    float L = 0.f;
#pragma unroll
    for (int kh = 0; kh < KSPLIT; ++kh) {
      wgt[kh] = __expf(m[kh] - M) * l[kh];
      L += wgt[kh];
    }
    float linv = 1.f / L;
#pragma unroll
    for (int kh = 0; kh < KSPLIT; ++kh) wgt[kh] *= linv;
  }

  f32x4 acc[8];
#pragma unroll
  for (int mb = 0; mb < 8; ++mb) acc[mb] = (f32x4){0.f, 0.f, 0.f, 0.f};

  const short* pob = po + ((size_t)b * NSP + n) * CCH;
#pragma unroll 2
  for (int kc = 0; kc < 8; ++kc) {
    int coff = kc * 32 + quad * 8;
    // merged B-frag (lane n, 8 consecutive c)
    bf16x8 f0 = *(const bf16x8*)(pob + 0 * (size_t)BB * NSP * CCH + coff);
    bf16x8 f1 = *(const bf16x8*)(pob + 1 * (size_t)BB * NSP * CCH + coff);
    bf16x8 f2 = *(const bf16x8*)(pob + 2 * (size_t)BB * NSP * CCH + coff);
    bf16x8 f3 = *(const bf16x8*)(pob + 3 * (size_t)BB * NSP * CCH + coff);
    bf16x8 bm;
#pragma unroll
    for (int e = 0; e < 8; ++e) {
      float f = wgt[0] * bf2f(f0[e]) + wgt[1] * bf2f(f1[e]) +
                wgt[2] * bf2f(f2[e]) + wgt[3] * bf2f(f3[e]);
      bm[e] = f2bf(f);
    }
#pragma unroll
    for (int mb = 0; mb < 8; ++mb) {
      bf16x8 af = *(const bf16x8*)(wpt + (size_t)(dh + mb * 16 + l16) * CCH + coff);
      acc[mb] = __builtin_amdgcn_mfma_f32_16x16x32_bf16(af, bm, acc[mb], 0, 0, 0);
    }
  }
  // epilogue: + bias + residual, /sqrt(2)
#pragma unroll
  for (int mb = 0; mb < 8; ++mb) {
#pragma unroll
    for (int r = 0; r < 4; ++r) {
      int d = dh + mb * 16 + quad * 4 + r;
      size_t off = ((size_t)b * CCH + d) * NSP + n;
      out[off] = (acc[mb][r] + bp[d] + x[off]) * RSQRT2;
    }
  }
}

extern "C" void kernel_launch(void* const* d_in, const int* in_sizes, int n_in,
                              void* d_out, int out_size, void* d_ws, size_t ws_size,
                              hipStream_t stream) {
  const float* x  = (const float*)d_in[0];
  const float* gw = (const float*)d_in[1];
  const float* gb = (const float*)d_in[2];
  const float* Wq = (const float*)d_in[3];
  const float* bq = (const float*)d_in[4];
  const float* Wk = (const float*)d_in[5];
  const float* bk = (const float*)d_in[6];
  const float* Wv = (const float*)d_in[7];
  const float* bv = (const float*)d_in[8];
  const float* Wp = (const float*)d_in[9];
  const float* bp = (const float*)d_in[10];
  float* out = (float*)d_out;

  const size_t SZ = (size_t)BB * CCH * NSP;  // 4.19M elems
  float* h   = (float*)d_ws;                 // gn out (qkv input)
  short* qb  = (short*)(h + SZ);             // bf16 [b][n][c], pre-scaled
  short* kb  = qb + SZ;                      // bf16 [b][n][c]
  short* vb  = kb + SZ;                      // bf16 [b][c][n]
  short* poT = vb + SZ;                      // bf16 [4][b][n][c] normalized
  float* pm  = (float*)(poT + (size_t)KSPLIT * SZ);  // [4][b][n]
  float* pl  = pm + (size_t)KSPLIT * BB * NSP;
  short* wpt = (short*)(pl + (size_t)KSPLIT * BB * NSP);  // bf16 [d][c]

  gn_kernel<<<dim3(BB * 32), dim3(256), 0, stream>>>(x, gw, gb, h);
  prep_wpt<<<dim3(4, 4), dim3(256), 0, stream>>>(Wp, wpt);
  qkv_kernel<<<dim3(64, 4, 12), dim3(256), 0, stream>>>(
      h, Wq, bq, Wk, bk, Wv, bv, qb, kb, vb);
  attn_kernel<<<dim3(256), dim3(512), 0, stream>>>(qb, kb, vb, poT, pm, pl);
  proj_kernel<<<dim3(64, 2, BB), dim3(256), 0, stream>>>(
      poT, pm, pl, wpt, bp, x, out);
}